// Round 4
// baseline (141.598 us; speedup 1.0000x reference)
//
#include <hip/hip_runtime.h>

// OrdLoss: N=2, C=16, D=32, H=128, W=128
// out = [ sum_{valid m} ( sum_{c<=t} log(clip(p)) + sum_{c>t} log(clip(1-p)) ) ] / ( -sum(valid) )
//
// R4: transpose the mapping. R1-R3 evidence: per-thread 16-load chains at
// exactly 2 MiB stride stay ~25 us even when L3-resident (hbm_bytes ~65 KB on
// replays) -- power-of-2 MiB strides alias L2-channel/L3-set interleave and
// serialize at the cache ports; sched_barrier was neutral (R3).
// Fix: thread <-> flat pred index. target is replicated along C, so t for a
// voxel is readable at a contiguous address; c=(f>>19)&15 is block-uniform.
// Every thread: 3 contiguous loads (pred float4, target int4, mask int4),
// 4 logs. 16384 blocks of pure streaming; count S from c==0 blocks only.

constexpr int kC    = 16;
constexpr int kDHW  = 32 * 128 * 128;        // 524288 = 2^19
constexpr int kTot  = 2 * kC * kDHW;         // 16777216 = 2^24 flat pred elements
constexpr int kBlock = 256;
constexpr int kElem  = kBlock * 4;           // 1024 elements per block
constexpr int kGrid  = kTot / kElem;         // 16384 blocks
constexpr int kCntBlocks = 2 * (kDHW / kElem); // 1024 c==0 blocks

__global__ __launch_bounds__(kBlock)
void ordloss_main(const float* __restrict__ pred,
                  const int*   __restrict__ target,
                  const int*   __restrict__ mask,
                  float*       __restrict__ bsum,
                  int*         __restrict__ bcnt) {
    const int f    = (blockIdx.x * kBlock + threadIdx.x) * 4;  // flat pred idx
    const int n    = f >> 23;                 // sample (block-uniform)
    const int c    = (f >> 19) & 15;          // channel (block-uniform)
    const int sp   = f & (kDHW - 1);          // spatial offset

    // all three streams are lane-contiguous
    const float4 p  = *reinterpret_cast<const float4*>(pred + f);
    const int4   tg = *reinterpret_cast<const int4*>(target + ((size_t)n << 23) + sp); // ch-0 copy
    const int4   mk = *reinterpret_cast<const int4*>(mask + ((size_t)n << 19) + sp);

    float x0 = (c <= tg.x) ? p.x : 1.0f - p.x;
    float x1 = (c <= tg.y) ? p.y : 1.0f - p.y;
    float x2 = (c <= tg.z) ? p.z : 1.0f - p.z;
    float x3 = (c <= tg.w) ? p.w : 1.0f - p.w;
    float lsum = (mk.x > 0 ? __logf(fmaxf(x0, 1e-8f)) : 0.f)
               + (mk.y > 0 ? __logf(fmaxf(x1, 1e-8f)) : 0.f)
               + (mk.z > 0 ? __logf(fmaxf(x2, 1e-8f)) : 0.f)
               + (mk.w > 0 ? __logf(fmaxf(x3, 1e-8f)) : 0.f);
    int   lcnt = (mk.x > 0) + (mk.y > 0) + (mk.z > 0) + (mk.w > 0);

    #pragma unroll
    for (int off = 32; off > 0; off >>= 1) {
        lsum += __shfl_down(lsum, off);
        lcnt += __shfl_down(lcnt, off);
    }
    __shared__ float swave[kBlock / 64];
    __shared__ int   cwave[kBlock / 64];
    const int lane = threadIdx.x & 63;
    const int wid  = threadIdx.x >> 6;
    if (lane == 0) { swave[wid] = lsum; cwave[wid] = lcnt; }
    __syncthreads();
    if (threadIdx.x == 0) {
        bsum[blockIdx.x] = swave[0] + swave[1] + swave[2] + swave[3];
        if (c == 0) {  // count voxels once, not once per channel
            const int sb = sp >> 10;                      // spatial block within (n,0)
            bcnt[(n << 9) + sb] = cwave[0] + cwave[1] + cwave[2] + cwave[3];
        }
    }
}

// 1 block, 256 threads: reduce 16384 float partials + 1024 int counts.
__global__ __launch_bounds__(kBlock)
void ordloss_reduce(const float* __restrict__ bsum,
                    const int*   __restrict__ bcnt,
                    float*       __restrict__ out) {
    double s = 0.0;
    #pragma unroll
    for (int j = 0; j < 16; ++j) {   // 16 x 256 float4 = 16384 floats
        const float4 v = *reinterpret_cast<const float4*>(bsum + (j * kBlock + threadIdx.x) * 4);
        s += (double)v.x + v.y + v.z + v.w;
    }
    const int4 c4 = *reinterpret_cast<const int4*>(bcnt + threadIdx.x * 4); // 1024 ints
    long c = (long)c4.x + c4.y + c4.z + c4.w;

    #pragma unroll
    for (int off = 32; off > 0; off >>= 1) {
        s += __shfl_down(s, off);
        c += __shfl_down(c, off);
    }
    __shared__ double sw[kBlock / 64];
    __shared__ long   cw[kBlock / 64];
    const int lane = threadIdx.x & 63;
    const int wid  = threadIdx.x >> 6;
    if (lane == 0) { sw[wid] = s; cw[wid] = c; }
    __syncthreads();
    if (threadIdx.x == 0) {
        double S = sw[0] + sw[1] + sw[2] + sw[3];
        long   C = cw[0] + cw[1] + cw[2] + cw[3];
        out[0] = (float)(S / (double)(-C));
    }
}

extern "C" void kernel_launch(void* const* d_in, const int* in_sizes, int n_in,
                              void* d_out, int out_size, void* d_ws, size_t ws_size,
                              hipStream_t stream) {
    const float* pred   = (const float*)d_in[0];
    const int*   target = (const int*)d_in[1];
    const int*   mask   = (const int*)d_in[2];
    float*       bsum   = (float*)d_ws;                              // 16384 floats
    int*         bcnt   = (int*)((char*)d_ws + kGrid * sizeof(float)); // 1024 ints
    float*       out    = (float*)d_out;

    ordloss_main<<<kGrid, kBlock, 0, stream>>>(pred, target, mask, bsum, bcnt);
    ordloss_reduce<<<1, kBlock, 0, stream>>>(bsum, bcnt, out);
}